// Round 2
// baseline (986.580 us; speedup 1.0000x reference)
//
#include <hip/hip_runtime.h>
#include <hip/hip_bf16.h>
#include <cmath>

#define TT 512
#define BB 32
#define EE 256
#define HH 128
#define KCRF 12
#define NEGF (-10000.0f)

#define RL(v, l) __uint_as_float(__builtin_amdgcn_readlane(__float_as_uint(v), (l)))

// ---------------------------------------------------------------------------
// K1: XG[row=t*32+b][col 0..1023] = embed[sent[b,t]] . W_cat[col]^T + bias
// (unchanged from round 1)
// ---------------------------------------------------------------------------
__global__ __launch_bounds__(256) void k1_xg(const int* __restrict__ sent,
    const float* __restrict__ embed,
    const float* __restrict__ Wf, const float* __restrict__ bf,
    const float* __restrict__ Wr, const float* __restrict__ br,
    float* __restrict__ XG)
{
  __shared__ __align__(16) float As[64][36];
  __shared__ __align__(16) float Bs[128][36];
  const int tid = threadIdx.x;
  const int m0 = (blockIdx.x >> 3) * 64;
  const int n0 = (blockIdx.x & 7) * 128;
  const int ty = tid >> 4, tx = tid & 15;
  float acc[4][8];
#pragma unroll
  for (int i = 0; i < 4; ++i)
#pragma unroll
    for (int j = 0; j < 8; ++j) acc[i][j] = 0.f;

  for (int k0 = 0; k0 < 256; k0 += 32) {
#pragma unroll
    for (int r = 0; r < 2; ++r) {
      int idx = tid + r * 256;
      int row = idx >> 3;
      int c4 = (idx & 7) << 2;
      int R = m0 + row;
      int t = R >> 5, b = R & 31;
      const float4 v = *(const float4*)(embed + (long)sent[b * TT + t] * 256 + k0 + c4);
      *(float4*)&As[row][c4] = v;
    }
#pragma unroll
    for (int r = 0; r < 4; ++r) {
      int idx = tid + r * 256;
      int row = idx >> 3;
      int c4 = (idx & 7) << 2;
      int col = n0 + row;
      const float* src = (col < 512) ? (Wf + (long)col * 256) : (Wr + (long)(col - 512) * 256);
      const float4 v = *(const float4*)(src + k0 + c4);
      *(float4*)&Bs[row][c4] = v;
    }
    __syncthreads();
#pragma unroll
    for (int kk = 0; kk < 32; ++kk) {
      float a[4], bv[8];
#pragma unroll
      for (int i = 0; i < 4; ++i) a[i] = As[ty * 4 + i][kk];
#pragma unroll
      for (int j = 0; j < 8; ++j) bv[j] = Bs[tx + 16 * j][kk];
#pragma unroll
      for (int i = 0; i < 4; ++i)
#pragma unroll
        for (int j = 0; j < 8; ++j) acc[i][j] = fmaf(a[i], bv[j], acc[i][j]);
    }
    __syncthreads();
  }
#pragma unroll
  for (int i = 0; i < 4; ++i) {
    int R = m0 + ty * 4 + i;
#pragma unroll
    for (int j = 0; j < 8; ++j) {
      int col = n0 + tx + 16 * j;
      float bias = (col < 512) ? bf[col] : br[col - 512];
      XG[(long)R * 1024 + col] = acc[i][j] + bias;
    }
  }
}

// ---------------------------------------------------------------------------
// K2: LSTM scans. One WG per (dir,batch). 512 threads, thread j owns gate
// column j (W_hh row in 128 VGPRs). h broadcast via v_readlane from a
// distributed ds_read_b64 (lane l holds h[2l],h[2l+1]) -> LDS traffic/step
// drops from 256KB to 4KB per CU; FMA reads h from SGPR.
// ---------------------------------------------------------------------------
__global__ __launch_bounds__(512, 2) void k2_scan(const float* __restrict__ XG,
    const float* __restrict__ Whf, const float* __restrict__ Whr,
    const float* __restrict__ h0, const float* __restrict__ c0,
    float* __restrict__ HS)
{
  const int wg = blockIdx.x;
  const int dir = wg >> 5;
  const int b = wg & 31;
  const int j = threadIdx.x;
  const int lane = j & 63;
  const float* Wh = dir ? Whr : Whf;

  float w[128];
#pragma unroll
  for (int i = 0; i < 32; ++i) {
    float4 v = *(const float4*)(Wh + (long)j * 128 + i * 4);
    w[4 * i + 0] = v.x; w[4 * i + 1] = v.y; w[4 * i + 2] = v.z; w[4 * i + 3] = v.w;
  }

  __shared__ __align__(16) float hs[128];
  __shared__ float gs[512];
  float c = 0.f;
  if (j < 128) {
    hs[j] = h0[(dir * 32 + b) * 128 + j];
    c = c0[(dir * 32 + b) * 128 + j];
  }
  __syncthreads();

  const int t0 = dir ? (TT - 1) : 0;
  float xg_cur = XG[((long)t0 * 32 + b) * 1024 + dir * 512 + j];
  const int gate = j >> 7;   // 0=i 1=f 2=g 3=o

  for (int s = 0; s < TT; ++s) {
    const int t = dir ? (TT - 1 - s) : s;
    float xg_nxt = 0.f;
    if (s + 1 < TT) {
      int tn = dir ? (TT - 2 - s) : (s + 1);
      xg_nxt = XG[((long)tn * 32 + b) * 1024 + dir * 512 + j];
    }
    // distributed read: this wave's lane l holds h[2l], h[2l+1]
    const float2 hp = *(const float2*)(hs + 2 * lane);
    float a0 = xg_cur, a1 = 0.f, a2 = 0.f, a3 = 0.f;
#pragma unroll
    for (int l = 0; l < 64; ++l) {
      const float sh0 = RL(hp.x, l);
      const float sh1 = RL(hp.y, l);
      if (l & 1) {
        a2 = fmaf(sh0, w[2 * l + 0], a2);
        a3 = fmaf(sh1, w[2 * l + 1], a3);
      } else {
        a0 = fmaf(sh0, w[2 * l + 0], a0);
        a1 = fmaf(sh1, w[2 * l + 1], a1);
      }
    }
    const float acc = (a0 + a1) + (a2 + a3);
    const float act = (gate == 2) ? tanhf(acc) : (1.f / (1.f + expf(-acc)));
    gs[j] = act;
    __syncthreads();           // gs ready; all hp reads of hs complete
    if (j < 128) {
      float ig = gs[j], fg = gs[128 + j], gg = gs[256 + j], og = gs[384 + j];
      c = fmaf(fg, c, ig * gg);
      float h = og * tanhf(c);
      hs[j] = h;
      HS[((long)t * 32 + b) * 256 + dir * 128 + j] = h;
    }
    __syncthreads();           // hs ready for next step
    xg_cur = xg_nxt;
  }
}

// ---------------------------------------------------------------------------
// K3: feats. FE layout [t][k][b]. (unchanged from round 1)
// ---------------------------------------------------------------------------
__global__ __launch_bounds__(64) void k3_feats(const float* __restrict__ HS,
    const float* __restrict__ Wout, const float* __restrict__ bout,
    float* __restrict__ FE)
{
  __shared__ __align__(16) float ws[12 * 256];
  __shared__ float bs[12];
  const int tid = threadIdx.x;
  for (int i = tid; i < 768; i += 64)
    ((float4*)ws)[i] = ((const float4*)Wout)[i];
  if (tid < 12) bs[tid] = bout[tid];
  __syncthreads();
  const long row = (long)blockIdx.x * 64 + tid;
  const float4* hp = (const float4*)(HS + row * 256);
  float acc[12];
#pragma unroll
  for (int k = 0; k < 12; ++k) acc[k] = bs[k];
  for (int e4 = 0; e4 < 64; ++e4) {
    float4 hv = hp[e4];
#pragma unroll
    for (int k = 0; k < 12; ++k) {
      const float4 wv = *(const float4*)&ws[k * 256 + e4 * 4];
      acc[k] = fmaf(hv.x, wv.x, acc[k]);
      acc[k] = fmaf(hv.y, wv.y, acc[k]);
      acc[k] = fmaf(hv.z, wv.z, acc[k]);
      acc[k] = fmaf(hv.w, wv.w, acc[k]);
    }
  }
  const int t = (int)(row >> 5), b = (int)(row & 31);
#pragma unroll
  for (int k = 0; k < 12; ++k) FE[((long)t * 12 + k) * 32 + b] = acc[k];
}

// ---------------------------------------------------------------------------
// K4: Viterbi. Double-buffered scores -> 1 barrier/step. Pointers packed as
// nibbles into LDS (512*32*12/2 = 96KB) by a 192-thread packer running one
// step behind; backtrace walks LDS (~120cy dep chain) instead of global.
// ---------------------------------------------------------------------------
__global__ __launch_bounds__(384) void k4_viterbi(const float* __restrict__ FE,
    const float* __restrict__ trans, int* __restrict__ out)
{
  __shared__ unsigned char nib[TT * 192];   // 98304 B
  __shared__ float sc[2][32][12];
  __shared__ float tr[144];
  __shared__ unsigned char stag[2][384];
  __shared__ int btag[32];
  const int tid = threadIdx.x;
  const int b = tid & 31, nxt = tid >> 5;
  if (tid < 144) tr[tid] = trans[tid];
  if (nxt == 0) {
#pragma unroll
    for (int p = 0; p < 12; ++p) sc[0][b][p] = (p == 9) ? 0.f : NEGF;  // START=9
  }
  __syncthreads();
  float fnext = FE[nxt * 32 + b];
  for (int t = 0; t < TT; ++t) {
    const int cur = t & 1;
    const float feat = fnext;
    if (t + 1 < TT) fnext = FE[(t + 1) * 384 + nxt * 32 + b];
    float best = -1e30f; int arg = 0;
#pragma unroll
    for (int p = 0; p < 12; ++p) {
      float v = sc[cur][b][p] + tr[nxt * 12 + p];
      if (v > best) { best = v; arg = p; }
    }
    sc[cur ^ 1][b][nxt] = best + feat;      // write other buffer: no WAR hazard
    stag[cur][b * 12 + nxt] = (unsigned char)arg;
    if (t > 0 && tid < 192) {               // pack step t-1 into nibbles
      const int bb = tid / 6, p = tid % 6;
      nib[(t - 1) * 192 + tid] =
          (unsigned char)(stag[cur ^ 1][bb * 12 + 2 * p] |
                          (stag[cur ^ 1][bb * 12 + 2 * p + 1] << 4));
    }
    __syncthreads();
  }
  if (tid < 192) {                          // pack final step (t=511, buffer 1)
    const int bb = tid / 6, p = tid % 6;
    nib[511 * 192 + tid] =
        (unsigned char)(stag[1][bb * 12 + 2 * p] | (stag[1][bb * 12 + 2 * p + 1] << 4));
  }
  if (nxt == 0) {                           // final buffer is sc[0] after 512 steps
    float best = -1e30f; int arg = 0;
#pragma unroll
    for (int p = 0; p < 12; ++p) {
      float v = sc[0][b][p] + tr[10 * 12 + p];   // STOP=10
      if (v > best) { best = v; arg = p; }
    }
    btag[b] = arg;
  }
  __syncthreads();
  if (tid < 32) {
    int tag = btag[b];
    for (int t = TT - 1; t >= 0; --t) {
      out[b * TT + t] = tag;
      if (t) {
        unsigned char v = nib[t * 192 + b * 6 + (tag >> 1)];
        tag = (tag & 1) ? (v >> 4) : (v & 15);
      }
    }
  }
}

// ---------------------------------------------------------------------------
extern "C" void kernel_launch(void* const* d_in, const int* in_sizes, int n_in,
                              void* d_out, int out_size, void* d_ws, size_t ws_size,
                              hipStream_t stream)
{
  const int* sent = (const int*)d_in[0];
  const float* h0 = (const float*)d_in[1];
  const float* c0 = (const float*)d_in[2];
  const float* embed = (const float*)d_in[3];
  const float* Wif = (const float*)d_in[4];
  const float* Whf = (const float*)d_in[5];
  const float* bf = (const float*)d_in[6];
  const float* Wir = (const float*)d_in[7];
  const float* Whr = (const float*)d_in[8];
  const float* br = (const float*)d_in[9];
  const float* Wout = (const float*)d_in[10];
  const float* bout = (const float*)d_in[11];
  const float* trans = (const float*)d_in[12];

  char* ws = (char*)d_ws;
  float* XG = (float*)ws;                                   // 67,108,864 B
  float* HS = (float*)(ws + 67108864);                      // 16,777,216 B
  float* FE = (float*)(ws + 67108864 + 16777216);           //    786,432 B
  int* out = (int*)d_out;

  hipLaunchKernelGGL(k1_xg, dim3(2048), dim3(256), 0, stream,
                     sent, embed, Wif, bf, Wir, br, XG);
  hipLaunchKernelGGL(k2_scan, dim3(64), dim3(512), 0, stream,
                     XG, Whf, Whr, h0, c0, HS);
  hipLaunchKernelGGL(k3_feats, dim3(256), dim3(64), 0, stream,
                     HS, Wout, bout, FE);
  hipLaunchKernelGGL(k4_viterbi, dim3(1), dim3(384), 0, stream,
                     FE, trans, out);
}

// Round 3
// 809.508 us; speedup vs baseline: 1.2187x; 1.2187x over previous
//
#include <hip/hip_runtime.h>
#include <hip/hip_bf16.h>
#include <cmath>

#define TT 512
#define BB 32
#define EE 256
#define HH 128
#define KCRF 12
#define NEGF (-10000.0f)

// ---------------------------------------------------------------------------
// K1: XG[row=t*32+b][col 0..1023] = embed[sent[b,t]] . W_cat[col]^T + bias
// (unchanged)
// ---------------------------------------------------------------------------
__global__ __launch_bounds__(256) void k1_xg(const int* __restrict__ sent,
    const float* __restrict__ embed,
    const float* __restrict__ Wf, const float* __restrict__ bf,
    const float* __restrict__ Wr, const float* __restrict__ br,
    float* __restrict__ XG)
{
  __shared__ __align__(16) float As[64][36];
  __shared__ __align__(16) float Bs[128][36];
  const int tid = threadIdx.x;
  const int m0 = (blockIdx.x >> 3) * 64;
  const int n0 = (blockIdx.x & 7) * 128;
  const int ty = tid >> 4, tx = tid & 15;
  float acc[4][8];
#pragma unroll
  for (int i = 0; i < 4; ++i)
#pragma unroll
    for (int j = 0; j < 8; ++j) acc[i][j] = 0.f;

  for (int k0 = 0; k0 < 256; k0 += 32) {
#pragma unroll
    for (int r = 0; r < 2; ++r) {
      int idx = tid + r * 256;
      int row = idx >> 3;
      int c4 = (idx & 7) << 2;
      int R = m0 + row;
      int t = R >> 5, b = R & 31;
      const float4 v = *(const float4*)(embed + (long)sent[b * TT + t] * 256 + k0 + c4);
      *(float4*)&As[row][c4] = v;
    }
#pragma unroll
    for (int r = 0; r < 4; ++r) {
      int idx = tid + r * 256;
      int row = idx >> 3;
      int c4 = (idx & 7) << 2;
      int col = n0 + row;
      const float* src = (col < 512) ? (Wf + (long)col * 256) : (Wr + (long)(col - 512) * 256);
      const float4 v = *(const float4*)(src + k0 + c4);
      *(float4*)&Bs[row][c4] = v;
    }
    __syncthreads();
#pragma unroll
    for (int kk = 0; kk < 32; ++kk) {
      float a[4], bv[8];
#pragma unroll
      for (int i = 0; i < 4; ++i) a[i] = As[ty * 4 + i][kk];
#pragma unroll
      for (int j = 0; j < 8; ++j) bv[j] = Bs[tx + 16 * j][kk];
#pragma unroll
      for (int i = 0; i < 4; ++i)
#pragma unroll
        for (int j = 0; j < 8; ++j) acc[i][j] = fmaf(a[i], bv[j], acc[i][j]);
    }
    __syncthreads();
  }
#pragma unroll
  for (int i = 0; i < 4; ++i) {
    int R = m0 + ty * 4 + i;
#pragma unroll
    for (int j = 0; j < 8; ++j) {
      int col = n0 + tx + 16 * j;
      float bias = (col < 512) ? bf[col] : br[col - 512];
      XG[(long)R * 1024 + col] = acc[i][j] + bias;
    }
  }
}

// ---------------------------------------------------------------------------
// K2: LSTM scans. One WG per (dir,batch), 512 threads, thread j owns gate
// column j. W_hh row held in TRUE VGPRs: amdgpu_waves_per_eu(1) lifts the
// register budget to 512 so the compiler stops parking w[] in AGPRs (rounds
// 1-2: VGPR_Count 76-80 => v_accvgpr_read per FMA per step). h is read via
// wave-uniform ds_read_b128 (LDS broadcast, bandwidth-free).
// Only 64 WGs exist (1 per CU) so occupancy above 2 waves/EU is unreachable
// anyway -- trading it for registers costs nothing.
// ---------------------------------------------------------------------------
__global__ __launch_bounds__(512) __attribute__((amdgpu_waves_per_eu(1)))
void k2_scan(const float* __restrict__ XG,
    const float* __restrict__ Whf, const float* __restrict__ Whr,
    const float* __restrict__ h0, const float* __restrict__ c0,
    float* __restrict__ HS)
{
  const int wg = blockIdx.x;
  const int dir = wg >> 5;
  const int b = wg & 31;
  const int j = threadIdx.x;
  const float* Wh = dir ? Whr : Whf;

  float4 w[32];
#pragma unroll
  for (int i = 0; i < 32; ++i)
    w[i] = *(const float4*)(Wh + (long)j * 128 + i * 4);

  __shared__ __align__(16) float hs[128];
  __shared__ float gs[512];
  float c = 0.f;
  if (j < 128) {
    hs[j] = h0[(dir * 32 + b) * 128 + j];
    c = c0[(dir * 32 + b) * 128 + j];
  }
  __syncthreads();

  // strength-reduced XG pointer walk
  const int t0 = dir ? (TT - 1) : 0;
  const long stepoff = dir ? -32768 : 32768;   // 32*1024 floats per t
  const float* xp = XG + ((long)t0 * 32 + b) * 1024 + dir * 512 + j;
  float xg_cur = *xp;
  const int gate = j >> 7;   // 0=i 1=f 2=g 3=o

  for (int s = 0; s < TT; ++s) {
    const int t = dir ? (TT - 1 - s) : s;
    float xg_nxt = 0.f;
    if (s + 1 < TT) { xp += stepoff; xg_nxt = *xp; }

    float a0 = xg_cur, a1 = 0.f, a2 = 0.f, a3 = 0.f;
#pragma unroll
    for (int i = 0; i < 32; ++i) {
      const float4 hv = *(const float4*)(hs + 4 * i);   // uniform -> broadcast
      a0 = fmaf(w[i].x, hv.x, a0);
      a1 = fmaf(w[i].y, hv.y, a1);
      a2 = fmaf(w[i].z, hv.z, a2);
      a3 = fmaf(w[i].w, hv.w, a3);
    }
    const float acc = (a0 + a1) + (a2 + a3);
    const float act = (gate == 2) ? tanhf(acc) : (1.f / (1.f + expf(-acc)));
    gs[j] = act;
    __syncthreads();           // gs ready; all reads of hs complete
    if (j < 128) {
      float ig = gs[j], fg = gs[128 + j], gg = gs[256 + j], og = gs[384 + j];
      c = fmaf(fg, c, ig * gg);
      float h = og * tanhf(c);
      hs[j] = h;
      HS[((long)t * 32 + b) * 256 + dir * 128 + j] = h;
    }
    __syncthreads();           // hs ready for next step
    xg_cur = xg_nxt;
  }
}

// ---------------------------------------------------------------------------
// K3: feats. FE layout [t][k][b]. (unchanged)
// ---------------------------------------------------------------------------
__global__ __launch_bounds__(64) void k3_feats(const float* __restrict__ HS,
    const float* __restrict__ Wout, const float* __restrict__ bout,
    float* __restrict__ FE)
{
  __shared__ __align__(16) float ws[12 * 256];
  __shared__ float bs[12];
  const int tid = threadIdx.x;
  for (int i = tid; i < 768; i += 64)
    ((float4*)ws)[i] = ((const float4*)Wout)[i];
  if (tid < 12) bs[tid] = bout[tid];
  __syncthreads();
  const long row = (long)blockIdx.x * 64 + tid;
  const float4* hp = (const float4*)(HS + row * 256);
  float acc[12];
#pragma unroll
  for (int k = 0; k < 12; ++k) acc[k] = bs[k];
  for (int e4 = 0; e4 < 64; ++e4) {
    float4 hv = hp[e4];
#pragma unroll
    for (int k = 0; k < 12; ++k) {
      const float4 wv = *(const float4*)&ws[k * 256 + e4 * 4];
      acc[k] = fmaf(hv.x, wv.x, acc[k]);
      acc[k] = fmaf(hv.y, wv.y, acc[k]);
      acc[k] = fmaf(hv.z, wv.z, acc[k]);
      acc[k] = fmaf(hv.w, wv.w, acc[k]);
    }
  }
  const int t = (int)(row >> 5), b = (int)(row & 31);
#pragma unroll
  for (int k = 0; k < 12; ++k) FE[((long)t * 12 + k) * 32 + b] = acc[k];
}

// ---------------------------------------------------------------------------
// K4: Viterbi, double-buffered scores (1 barrier/step), nibble-packed
// pointers in LDS for the backtrace. (unchanged from round 2 -- it worked)
// ---------------------------------------------------------------------------
__global__ __launch_bounds__(384) void k4_viterbi(const float* __restrict__ FE,
    const float* __restrict__ trans, int* __restrict__ out)
{
  __shared__ unsigned char nib[TT * 192];   // 98304 B
  __shared__ float sc[2][32][12];
  __shared__ float tr[144];
  __shared__ unsigned char stag[2][384];
  __shared__ int btag[32];
  const int tid = threadIdx.x;
  const int b = tid & 31, nxt = tid >> 5;
  if (tid < 144) tr[tid] = trans[tid];
  if (nxt == 0) {
#pragma unroll
    for (int p = 0; p < 12; ++p) sc[0][b][p] = (p == 9) ? 0.f : NEGF;  // START=9
  }
  __syncthreads();
  float fnext = FE[nxt * 32 + b];
  for (int t = 0; t < TT; ++t) {
    const int cur = t & 1;
    const float feat = fnext;
    if (t + 1 < TT) fnext = FE[(t + 1) * 384 + nxt * 32 + b];
    float best = -1e30f; int arg = 0;
#pragma unroll
    for (int p = 0; p < 12; ++p) {
      float v = sc[cur][b][p] + tr[nxt * 12 + p];
      if (v > best) { best = v; arg = p; }
    }
    sc[cur ^ 1][b][nxt] = best + feat;
    stag[cur][b * 12 + nxt] = (unsigned char)arg;
    if (t > 0 && tid < 192) {
      const int bb = tid / 6, p = tid % 6;
      nib[(t - 1) * 192 + tid] =
          (unsigned char)(stag[cur ^ 1][bb * 12 + 2 * p] |
                          (stag[cur ^ 1][bb * 12 + 2 * p + 1] << 4));
    }
    __syncthreads();
  }
  if (tid < 192) {
    const int bb = tid / 6, p = tid % 6;
    nib[511 * 192 + tid] =
        (unsigned char)(stag[1][bb * 12 + 2 * p] | (stag[1][bb * 12 + 2 * p + 1] << 4));
  }
  if (nxt == 0) {
    float best = -1e30f; int arg = 0;
#pragma unroll
    for (int p = 0; p < 12; ++p) {
      float v = sc[0][b][p] + tr[10 * 12 + p];   // STOP=10
      if (v > best) { best = v; arg = p; }
    }
    btag[b] = arg;
  }
  __syncthreads();
  if (tid < 32) {
    int tag = btag[b];
    for (int t = TT - 1; t >= 0; --t) {
      out[b * TT + t] = tag;
      if (t) {
        unsigned char v = nib[t * 192 + b * 6 + (tag >> 1)];
        tag = (tag & 1) ? (v >> 4) : (v & 15);
      }
    }
  }
}

// ---------------------------------------------------------------------------
extern "C" void kernel_launch(void* const* d_in, const int* in_sizes, int n_in,
                              void* d_out, int out_size, void* d_ws, size_t ws_size,
                              hipStream_t stream)
{
  const int* sent = (const int*)d_in[0];
  const float* h0 = (const float*)d_in[1];
  const float* c0 = (const float*)d_in[2];
  const float* embed = (const float*)d_in[3];
  const float* Wif = (const float*)d_in[4];
  const float* Whf = (const float*)d_in[5];
  const float* bf = (const float*)d_in[6];
  const float* Wir = (const float*)d_in[7];
  const float* Whr = (const float*)d_in[8];
  const float* br = (const float*)d_in[9];
  const float* Wout = (const float*)d_in[10];
  const float* bout = (const float*)d_in[11];
  const float* trans = (const float*)d_in[12];

  char* ws = (char*)d_ws;
  float* XG = (float*)ws;                                   // 67,108,864 B
  float* HS = (float*)(ws + 67108864);                      // 16,777,216 B
  float* FE = (float*)(ws + 67108864 + 16777216);           //    786,432 B
  int* out = (int*)d_out;

  hipLaunchKernelGGL(k1_xg, dim3(2048), dim3(256), 0, stream,
                     sent, embed, Wif, bf, Wir, br, XG);
  hipLaunchKernelGGL(k2_scan, dim3(64), dim3(512), 0, stream,
                     XG, Whf, Whr, h0, c0, HS);
  hipLaunchKernelGGL(k3_feats, dim3(256), dim3(64), 0, stream,
                     HS, Wout, bout, FE);
  hipLaunchKernelGGL(k4_viterbi, dim3(1), dim3(384), 0, stream,
                     FE, trans, out);
}